// Round 2
// baseline (2602.632 us; speedup 1.0000x reference)
//
#include <hip/hip_runtime.h>
#include <hip/hip_bf16.h>

typedef short short8 __attribute__((ext_vector_type(8)));
typedef float float4v __attribute__((ext_vector_type(4)));
typedef __hip_bfloat16 b16;
typedef unsigned short ushort_t;

#define T_ 128

__device__ __forceinline__ float sigm(float x) { return 1.0f / (1.0f + __expf(-x)); }
__device__ __forceinline__ float blo(unsigned u) { return __uint_as_float(u << 16); }
__device__ __forceinline__ float bhi(unsigned u) { return __uint_as_float(u & 0xffff0000u); }
__device__ __forceinline__ unsigned pack2bf(float a, float b) {
  b16 ha = __float2bfloat16(a), hb = __float2bfloat16(b);
  return (unsigned)*(ushort_t*)&ha | ((unsigned)*(ushort_t*)&hb << 16);
}

__device__ __forceinline__ void load_lds16(const void* g, void* l) {
  __builtin_amdgcn_global_load_lds((const __attribute__((address_space(1))) void*)g,
                                   (__attribute__((address_space(3))) void*)l, 16, 0, 0);
}

// ---------------------------------------------------------------- gather E rows -> bf16, t-major rows (r = t*128 + b)
__global__ void gather_x(const int* __restrict__ article, const float* __restrict__ E,
                         b16* __restrict__ Xg) {
  int r = blockIdx.x;
  int b = r & 127, t = r >> 7;
  int tok = article[b * T_ + t];
  const float4* src = (const float4*)(E + (size_t)tok * 1024);
  float4 v = src[threadIdx.x];
  b16* dst = Xg + (size_t)r * 1024 + threadIdx.x * 4;
  dst[0] = __float2bfloat16(v.x);
  dst[1] = __float2bfloat16(v.y);
  dst[2] = __float2bfloat16(v.z);
  dst[3] = __float2bfloat16(v.w);
}

// ---------------------------------------------------------------- stack two fp32 [rows_each x k] into bf16 [2*rows_each x k]
__global__ void cvt_cat2(const float* __restrict__ s0, const float* __restrict__ s1,
                         b16* __restrict__ out, int rows_each, int k, int total) {
  for (int idx = blockIdx.x * 256 + threadIdx.x; idx < total; idx += gridDim.x * 256) {
    int row = idx / k, col = idx - row * k;
    float v = (row < rows_each) ? s0[(size_t)row * k + col]
                                : s1[(size_t)(row - rows_each) * k + col];
    out[idx] = __float2bfloat16(v);
  }
}

// ---------------------------------------------------------------- bias0[j] = (bih+bhh) per cell, j in [0,4096)
__global__ void prep_bias(const float* bf1, const float* bf2, const float* bb1,
                          const float* bb2, float* out) {
  int j = blockIdx.x * 256 + threadIdx.x;
  int c = j >> 11, jj = j & 2047;
  out[j] = c ? (bb1[jj] + bb2[jj]) : (bf1[jj] + bf2[jj]);
}

// ---------------------------------------------------------------- pad dW [1074x2148] -> bf16 [1152x2176], db -> dbpad[1152]
__global__ void prep_dw(const float* __restrict__ dW, const float* __restrict__ db,
                        b16* __restrict__ dWpad, float* __restrict__ dbpad) {
  int idx = blockIdx.x * 256 + threadIdx.x;  // grid sized to exactly 1152*2176
  int r = idx / 2176, k = idx - r * 2176;
  float v = (r < 1074 && k < 2148) ? dW[(size_t)r * 2148 + k] : 0.0f;
  dWpad[idx] = __float2bfloat16(v);
  if (idx < 1152) dbpad[idx] = (idx < 1074) ? db[idx] : 0.0f;
}

// ---------------------------------------------------------------- bf16 GEMM: C[MxN] = A[MxK] @ B2[NxK]^T + bias (opt tanh)
// 128x128 tile, BK=64, global_load_lds(16B) staging with XOR chunk swizzle.
__global__ __launch_bounds__(256) void gemm_bt(
    const b16* __restrict__ A, const b16* __restrict__ B2, b16* __restrict__ C,
    const float* __restrict__ bias, int M, int N, int K, int act) {
  __shared__ __align__(16) b16 As[128 * 64];
  __shared__ __align__(16) b16 Bs[128 * 64];
  const int tid = threadIdx.x;
  const int w = tid >> 6, lane = tid & 63;
  const int quad = lane >> 4, lane16 = lane & 15;
  const int m0 = blockIdx.y * 128, n0 = blockIdx.x * 128;
  const int wm = (w >> 1) * 64, wn = (w & 1) * 64;
  float4v acc[4][4] = {};
  for (int kt = 0; kt < K; kt += 64) {
    __syncthreads();
    #pragma unroll
    for (int i = 0; i < 4; ++i) {
      int s = (i * 4 + w) * 64 + lane;
      int rr = s >> 3, ch = s & 7;
      int gch = ch ^ (rr & 7);
      load_lds16(A + (size_t)(m0 + rr) * K + kt + gch * 8, (char*)As + (i * 4 + w) * 1024);
      load_lds16(B2 + (size_t)(n0 + rr) * K + kt + gch * 8, (char*)Bs + (i * 4 + w) * 1024);
    }
    __syncthreads();
    #pragma unroll
    for (int ks = 0; ks < 2; ++ks) {
      short8 af[4], bfr[4];
      #pragma unroll
      for (int a = 0; a < 4; ++a) {
        int rr = wm + a * 16 + lane16;
        int gg = ks * 4 + quad;
        af[a] = *(const short8*)(As + rr * 64 + (gg ^ (rr & 7)) * 8);
      }
      #pragma unroll
      for (int b = 0; b < 4; ++b) {
        int rr = wn + b * 16 + lane16;
        int gg = ks * 4 + quad;
        bfr[b] = *(const short8*)(Bs + rr * 64 + (gg ^ (rr & 7)) * 8);
      }
      #pragma unroll
      for (int a = 0; a < 4; ++a)
        #pragma unroll
        for (int b = 0; b < 4; ++b)
          acc[a][b] = __builtin_amdgcn_mfma_f32_16x16x32_bf16(af[a], bfr[b], acc[a][b], 0, 0, 0);
    }
  }
  #pragma unroll
  for (int a = 0; a < 4; ++a) {
    #pragma unroll
    for (int b = 0; b < 4; ++b) {
      int col = n0 + wn + b * 16 + lane16;
      float bv = bias ? bias[col] : 0.0f;
      #pragma unroll
      for (int rg = 0; rg < 4; ++rg) {
        int row = m0 + wm + a * 16 + quad * 4 + rg;
        float v = acc[a][b][rg] + bv;
        if (act) v = tanhf(v);
        C[(size_t)row * N + col] = __float2bfloat16(v);
      }
    }
  }
}

// ---------------------------------------------------------------- persistent LSTM scan (one layer, 2 cells)
// 256 blocks x 512 thr. Block: cell c, hidden slice hs=p*32, batch slice rb=r*16.
// Gates for step t: Xproj[t] (precomputed, incl. biases) + h(t-1) @ Whh^T.
//
// h exchange through the MALL (sc0 sc1). Per-producer-WAVE flag words:
// producer wave (block (p,d), wave pw in 0..3) covers rows rb+4*pw..+4, cols
// hs..hs+32 of cell c. After its h stores, the wave drains (wave-level
// vmcnt(0) covers all 64 lanes' stores) and lane0 plain-stores flag
// [t][d][p*4+pw] = 1 (sc0 sc1, no RMW -> no 16-way atomic serialization).
// Consumer staging thread (srow, schunk) needs exactly one producer wave's
// slice: flag index (schunk>>1)*4 + (srow>>2). It polls that word, then
// immediately pulls its 32B -> discovery overlaps staging, no poll barrier.
// Barriers: 2/step. [B] post-stage orders As-writes(t) before MFMA-reads(t);
// [C] post-gbuf orders gbuf-writes(t) before cell-reads(t). As-writes(t+1)
// are program-ordered after [C](t) in every wave, and MFMA-reads(t) complete
// before each wave reaches [C](t) -> no trailing barrier needed.
__global__ __launch_bounds__(512) void lstm_scan(
    const b16* __restrict__ Xproj,   // [128*128][4096]
    const b16* __restrict__ Whh,     // [2][2048][512] bf16
    b16* __restrict__ hseq,          // [128*128][1024]
    int* __restrict__ flags) {       // [128][16][64] ints
  __shared__ __align__(16) b16 As[16 * 528];
  __shared__ __align__(16) float gbuf[8][16][16];
  const int tid = threadIdx.x;
  const int bid = blockIdx.x;
  const int p = bid >> 4, d = bid & 15;   // domain d = c*8 + r
  const int c = d >> 3, r = d & 7;
  const int rb = r * 16, hs = p * 32;
  const int w = tid >> 6, lane = tid & 63;
  const int quad = lane >> 4, lane16 = lane & 15;
  const int gate = w >> 1, half = w & 1;
  const int colbase = gate * 512 + hs + half * 16;

  // resident weight fragments: wave w owns 16 gate-columns, all K=512
  short8 bfrag[16];
  {
    const b16* wp = Whh + ((size_t)(c * 2048 + colbase + lane16)) * 512 + quad * 8;
    #pragma unroll
    for (int ks = 0; ks < 16; ++ks) bfrag[ks] = *(const short8*)(wp + ks * 32);
  }
  // cell-update ownership: threads 0..255, batch row rb+bloc, hidden pair hs+2*hp
  const int bloc = tid >> 4, hp = tid & 15;
  // staging ownership: row srow (16 rows), 32B chunk schunk
  const int srow = tid >> 5, schunk = tid & 31;
  float cs0 = 0.0f, cs1 = 0.0f;

  for (int t = 0; t < T_; ++t) {
    // prefetch Xproj gate dwords early (plain cached loads)
    unsigned xpr[4];
    if (tid < 256) {
      const unsigned* xb =
          (const unsigned*)(Xproj + ((size_t)t * 128 + rb + bloc) * 4096 + c * 2048 + hs + hp * 2);
      #pragma unroll
      for (int g4 = 0; g4 < 4; ++g4) xpr[g4] = xb[g4 * 256];
    }
    float4v acc0 = {0.f, 0.f, 0.f, 0.f}, acc1 = {0.f, 0.f, 0.f, 0.f};
    float4v acc2 = {0.f, 0.f, 0.f, 0.f}, acc3 = {0.f, 0.f, 0.f, 0.f};
    if (t > 0) {
      // poll the single producer-wave flag guarding this thread's 32B slice
      const int* fp = flags + (((t - 1) * 16 + d) << 6) + (schunk >> 1) * 4 + (srow >> 2);
      int fv;
      do {
        asm volatile("global_load_dword %0, %1, off sc0 sc1\n\t"
                     "s_waitcnt vmcnt(0)"
                     : "=v"(fv) : "v"(fp) : "memory");
      } while (fv == 0);
      // pull h(t-1)[rb+srow, cell c, 16 elems at schunk*16] from the MALL
      const b16* g = hseq + ((size_t)(t - 1) * 128 + rb + srow) * 1024 + c * 512 + schunk * 16;
      uint4 v0, v1;
      asm volatile("global_load_dwordx4 %0, %2, off sc0 sc1\n\t"
                   "global_load_dwordx4 %1, %2, off offset:16 sc0 sc1"
                   : "=&v"(v0), "=&v"(v1) : "v"(g) : "memory");
      asm volatile("s_waitcnt vmcnt(0)" ::: "memory");
      *(uint4*)(As + srow * 528 + schunk * 16) = v0;
      *(uint4*)(As + srow * 528 + schunk * 16 + 8) = v1;
      __syncthreads();                                   // [B]
      // 4 independent accumulation chains to break MFMA latency serialization
      #pragma unroll
      for (int ks = 0; ks < 16; ks += 4) {
        short8 a0 = *(const short8*)(As + lane16 * 528 + (ks + 0) * 32 + quad * 8);
        short8 a1 = *(const short8*)(As + lane16 * 528 + (ks + 1) * 32 + quad * 8);
        short8 a2 = *(const short8*)(As + lane16 * 528 + (ks + 2) * 32 + quad * 8);
        short8 a3 = *(const short8*)(As + lane16 * 528 + (ks + 3) * 32 + quad * 8);
        acc0 = __builtin_amdgcn_mfma_f32_16x16x32_bf16(a0, bfrag[ks + 0], acc0, 0, 0, 0);
        acc1 = __builtin_amdgcn_mfma_f32_16x16x32_bf16(a1, bfrag[ks + 1], acc1, 0, 0, 0);
        acc2 = __builtin_amdgcn_mfma_f32_16x16x32_bf16(a2, bfrag[ks + 2], acc2, 0, 0, 0);
        acc3 = __builtin_amdgcn_mfma_f32_16x16x32_bf16(a3, bfrag[ks + 3], acc3, 0, 0, 0);
      }
    }
    #pragma unroll
    for (int rg = 0; rg < 4; ++rg)
      gbuf[w][quad * 4 + rg][lane16] = acc0[rg] + acc1[rg] + acc2[rg] + acc3[rg];
    __syncthreads();                                     // [C]
    if (tid < 256) {  // cell update: 2 adjacent hidden units per thread
      const size_t xrow = (size_t)t * 128 + rb + bloc;
      const int hhalf = hp >> 3;          // (2*hp)>>4
      const int ci = 2 * (hp & 7);        // (2*hp)&15
      float g0[4], g1[4];
      #pragma unroll
      for (int g4 = 0; g4 < 4; ++g4) {
        float2 gv = *(const float2*)&gbuf[g4 * 2 + hhalf][bloc][ci];
        g0[g4] = gv.x + blo(xpr[g4]);
        g1[g4] = gv.y + bhi(xpr[g4]);
      }
      float i0 = sigm(g0[0]), f0 = sigm(g0[1]), gg0 = tanhf(g0[2]), o0 = sigm(g0[3]);
      float i1 = sigm(g1[0]), f1 = sigm(g1[1]), gg1 = tanhf(g1[2]), o1 = sigm(g1[3]);
      cs0 = f0 * cs0 + i0 * gg0;
      cs1 = f1 * cs1 + i1 * gg1;
      unsigned hv = pack2bf(o0 * tanhf(cs0), o1 * tanhf(cs1));
      unsigned* ha = (unsigned*)(hseq + xrow * 1024 + c * 512 + hs) + hp;
      asm volatile("global_store_dword %0, %1, off sc0 sc1" :: "v"(ha), "v"(hv) : "memory");
      // per-wave publish: drain THIS wave's stores (vmcnt is wave-level),
      // then lane0 marks the wave's 4-row slice ready.
      asm volatile("s_waitcnt vmcnt(0)" ::: "memory");
      if (lane == 0) {
        int one = 1;
        const int* fq = flags + ((t * 16 + d) << 6) + p * 4 + w;
        asm volatile("global_store_dword %0, %1, off sc0 sc1" :: "v"(fq), "v"(one) : "memory");
      }
    }
    // no trailing barrier: [C](t) already orders next step's As/gbuf writes
    // after this step's reads (see header comment).
  }
}

// ---------------------------------------------------------------- build rep row [target | context | src_e | pad], write target fp32 out
__global__ void build_rep(const int* __restrict__ article, const int* __restrict__ positions,
                          const int* __restrict__ srcs, const float* __restrict__ E,
                          const float* __restrict__ src_emb, const b16* __restrict__ Xg,
                          const b16* __restrict__ h2seq, b16* __restrict__ rep,
                          float* __restrict__ out) {
  int b = blockIdx.x, tid = threadIdx.x;
  int pos = positions[b], sc = srcs[b];
  for (int k = tid; k < 2176; k += 256) {
    b16 v;
    if (k < 1024)      v = Xg[((size_t)pos * 128 + b) * 1024 + k];
    else if (k < 2048) v = h2seq[((size_t)127 * 128 + b) * 1024 + (k - 1024)];
    else if (k < 2148) v = __float2bfloat16(src_emb[sc * 100 + (k - 2048)]);
    else               v = __float2bfloat16(0.0f);
    rep[(size_t)b * 2176 + k] = v;
  }
  int tok = article[b * T_ + pos];
  for (int k = tid; k < 1024; k += 256)
    out[512 + b * 1024 + k] = E[(size_t)tok * 1024 + k];
}

// ---------------------------------------------------------------- logits + probs
__global__ void classifier(const b16* __restrict__ feat, const float* __restrict__ cW,
                           const float* __restrict__ cb, float* __restrict__ out) {
  __shared__ float red[256];
  int tid = threadIdx.x;
  int pairIdx = tid >> 3, jc = tid & 7;
  int bl = pairIdx >> 1, l = pairIdx & 1;
  int b = blockIdx.x * 16 + bl;
  int j0 = jc * 135, j1 = (j0 + 135 < 1074) ? j0 + 135 : 1074;
  float s = 0.f;
  for (int j = j0; j < j1; ++j)
    s += __bfloat162float(feat[(size_t)b * 1152 + j]) * cW[l * 1074 + j];
  red[tid] = s;
  __syncthreads();
  if (jc == 0) {
    float tot = 0.f;
    #pragma unroll
    for (int q = 0; q < 8; ++q) tot += red[pairIdx * 8 + q];
    tot += cb[l];
    out[b * 2 + l] = tot;
    out[256 + b * 2 + l] = 1.0f / (1.0f + __expf(-tot));
  }
}

// ----------------------------------------------------------------
extern "C" void kernel_launch(void* const* d_in, const int* in_sizes, int n_in,
                              void* d_out, int out_size, void* d_ws, size_t ws_size,
                              hipStream_t stream) {
  const int* article = (const int*)d_in[0];
  const int* positions = (const int*)d_in[1];
  const int* srcs = (const int*)d_in[2];
  const float* E = (const float*)d_in[3];
  const float* src_emb = (const float*)d_in[4];
  const float* Wih0f = (const float*)d_in[5];
  const float* Whh0f = (const float*)d_in[6];
  const float* bih0f = (const float*)d_in[7];
  const float* bhh0f = (const float*)d_in[8];
  const float* Wih0b = (const float*)d_in[9];
  const float* Whh0b = (const float*)d_in[10];
  const float* bih0b = (const float*)d_in[11];
  const float* bhh0b = (const float*)d_in[12];
  const float* Wih1f = (const float*)d_in[13];
  const float* Whh1f = (const float*)d_in[14];
  const float* bih1f = (const float*)d_in[15];
  const float* bhh1f = (const float*)d_in[16];
  const float* Wih1b = (const float*)d_in[17];
  const float* Whh1b = (const float*)d_in[18];
  const float* bih1b = (const float*)d_in[19];
  const float* bhh1b = (const float*)d_in[20];
  const float* dW = (const float*)d_in[21];
  const float* db = (const float*)d_in[22];
  const float* cW = (const float*)d_in[23];
  const float* cb = (const float*)d_in[24];

  char* ws = (char*)d_ws;
  size_t off = 0;
  auto carve = [&](size_t bytes) -> void* {
    void* p = ws + off;
    off += (bytes + 255) & ~(size_t)255;
    return p;
  };
  b16* Xg    = (b16*)carve((size_t)16384 * 1024 * 2);
  b16* h1seq = (b16*)carve((size_t)16384 * 1024 * 2);
  b16* h2seq = (b16*)carve((size_t)16384 * 1024 * 2);
  b16* Xproj = (b16*)carve((size_t)16384 * 4096 * 2);  // reused for layer0 and layer1
  b16* W0cat = (b16*)carve((size_t)4096 * 1024 * 2);
  b16* W1cat = (b16*)carve((size_t)4096 * 1024 * 2);
  b16* Whh0  = (b16*)carve((size_t)2 * 2048 * 512 * 2);
  b16* Whh1  = (b16*)carve((size_t)2 * 2048 * 512 * 2);
  b16* dWpad = (b16*)carve((size_t)1152 * 2176 * 2);
  b16* rep   = (b16*)carve((size_t)128 * 2176 * 2);
  b16* feat  = (b16*)carve((size_t)128 * 1152 * 2);
  float* bias0 = (float*)carve(4096 * 4);
  float* bias1 = (float*)carve(4096 * 4);
  float* dbpad = (float*)carve(1152 * 4);
  int* flags1 = (int*)carve(128 * 16 * 64 * 4);
  int* flags2 = (int*)carve(128 * 16 * 64 * 4);
  (void)ws_size; (void)in_sizes; (void)n_in; (void)out_size;

  hipMemsetAsync(flags1, 0, 2 * 128 * 16 * 64 * 4, stream);

  gather_x<<<16384, 256, 0, stream>>>(article, E, Xg);
  cvt_cat2<<<8192, 256, 0, stream>>>(Wih0f, Wih0b, W0cat, 2048, 1024, 4096 * 1024);
  cvt_cat2<<<8192, 256, 0, stream>>>(Wih1f, Wih1b, W1cat, 2048, 1024, 4096 * 1024);
  cvt_cat2<<<8192, 256, 0, stream>>>(Whh0f, Whh0b, Whh0, 2048, 512, 4096 * 512);
  cvt_cat2<<<8192, 256, 0, stream>>>(Whh1f, Whh1b, Whh1, 2048, 512, 4096 * 512);
  prep_bias<<<16, 256, 0, stream>>>(bih0f, bhh0f, bih0b, bhh0b, bias0);
  prep_bias<<<16, 256, 0, stream>>>(bih1f, bhh1f, bih1b, bhh1b, bias1);
  prep_dw<<<9792, 256, 0, stream>>>(dW, db, dWpad, dbpad);

  gemm_bt<<<dim3(32, 128), 256, 0, stream>>>(Xg, W0cat, Xproj, bias0, 16384, 4096, 1024, 0);
  lstm_scan<<<256, 512, 0, stream>>>(Xproj, Whh0, h1seq, flags1);
  gemm_bt<<<dim3(32, 128), 256, 0, stream>>>(h1seq, W1cat, Xproj, bias1, 16384, 4096, 1024, 0);
  lstm_scan<<<256, 512, 0, stream>>>(Xproj, Whh1, h2seq, flags2);

  build_rep<<<128, 256, 0, stream>>>(article, positions, srcs, E, src_emb, Xg, h2seq, rep,
                                     (float*)d_out);
  gemm_bt<<<dim3(9, 1), 256, 0, stream>>>(rep, dWpad, feat, dbpad, 128, 1152, 2176, 1);
  classifier<<<8, 256, 0, stream>>>(feat, cW, cb, (float*)d_out);
}

// Round 4
// 1493.162 us; speedup vs baseline: 1.7430x; 1.7430x over previous
//
#include <hip/hip_runtime.h>
#include <hip/hip_bf16.h>

typedef short short8 __attribute__((ext_vector_type(8)));
typedef float float4v __attribute__((ext_vector_type(4)));
typedef __hip_bfloat16 b16;
typedef unsigned short ushort_t;

#define T_ 128

__device__ __forceinline__ float sigm(float x) { return 1.0f / (1.0f + __expf(-x)); }
__device__ __forceinline__ float blo(unsigned u) { return __uint_as_float(u << 16); }
__device__ __forceinline__ float bhi(unsigned u) { return __uint_as_float(u & 0xffff0000u); }
__device__ __forceinline__ unsigned pack2bf(float a, float b) {
  b16 ha = __float2bfloat16(a), hb = __float2bfloat16(b);
  return (unsigned)*(ushort_t*)&ha | ((unsigned)*(ushort_t*)&hb << 16);
}

__device__ __forceinline__ void load_lds16(const void* g, void* l) {
  __builtin_amdgcn_global_load_lds((const __attribute__((address_space(1))) void*)g,
                                   (__attribute__((address_space(3))) void*)l, 16, 0, 0);
}

// ---------------------------------------------------------------- gather E rows -> bf16, t-major rows (r = t*128 + b)
__global__ void gather_x(const int* __restrict__ article, const float* __restrict__ E,
                         b16* __restrict__ Xg) {
  int r = blockIdx.x;
  int b = r & 127, t = r >> 7;
  int tok = article[b * T_ + t];
  const float4* src = (const float4*)(E + (size_t)tok * 1024);
  float4 v = src[threadIdx.x];
  b16* dst = Xg + (size_t)r * 1024 + threadIdx.x * 4;
  dst[0] = __float2bfloat16(v.x);
  dst[1] = __float2bfloat16(v.y);
  dst[2] = __float2bfloat16(v.z);
  dst[3] = __float2bfloat16(v.w);
}

// ---------------------------------------------------------------- stack two fp32 [rows_each x k] into bf16 [2*rows_each x k]
__global__ void cvt_cat2(const float* __restrict__ s0, const float* __restrict__ s1,
                         b16* __restrict__ out, int rows_each, int k, int total) {
  for (int idx = blockIdx.x * 256 + threadIdx.x; idx < total; idx += gridDim.x * 256) {
    int row = idx / k, col = idx - row * k;
    float v = (row < rows_each) ? s0[(size_t)row * k + col]
                                : s1[(size_t)(row - rows_each) * k + col];
    out[idx] = __float2bfloat16(v);
  }
}

// ---------------------------------------------------------------- bias0[j] = (bih+bhh) per cell, j in [0,4096)
__global__ void prep_bias(const float* bf1, const float* bf2, const float* bb1,
                          const float* bb2, float* out) {
  int j = blockIdx.x * 256 + threadIdx.x;
  int c = j >> 11, jj = j & 2047;
  out[j] = c ? (bb1[jj] + bb2[jj]) : (bf1[jj] + bf2[jj]);
}

// ---------------------------------------------------------------- pad dW [1074x2148] -> bf16 [1152x2176], db -> dbpad[1152]
__global__ void prep_dw(const float* __restrict__ dW, const float* __restrict__ db,
                        b16* __restrict__ dWpad, float* __restrict__ dbpad) {
  int idx = blockIdx.x * 256 + threadIdx.x;  // grid sized to exactly 1152*2176
  int r = idx / 2176, k = idx - r * 2176;
  float v = (r < 1074 && k < 2148) ? dW[(size_t)r * 2148 + k] : 0.0f;
  dWpad[idx] = __float2bfloat16(v);
  if (idx < 1152) dbpad[idx] = (idx < 1074) ? db[idx] : 0.0f;
}

// ---------------------------------------------------------------- bf16 GEMM: C[MxN] = A[MxK] @ B2[NxK]^T + bias (opt tanh)
// 128x128 tile, BK=64, global_load_lds(16B) staging with XOR chunk swizzle.
__global__ __launch_bounds__(256) void gemm_bt(
    const b16* __restrict__ A, const b16* __restrict__ B2, b16* __restrict__ C,
    const float* __restrict__ bias, int M, int N, int K, int act) {
  __shared__ __align__(16) b16 As[128 * 64];
  __shared__ __align__(16) b16 Bs[128 * 64];
  const int tid = threadIdx.x;
  const int w = tid >> 6, lane = tid & 63;
  const int quad = lane >> 4, lane16 = lane & 15;
  const int m0 = blockIdx.y * 128, n0 = blockIdx.x * 128;
  const int wm = (w >> 1) * 64, wn = (w & 1) * 64;
  float4v acc[4][4] = {};
  for (int kt = 0; kt < K; kt += 64) {
    __syncthreads();
    #pragma unroll
    for (int i = 0; i < 4; ++i) {
      int s = (i * 4 + w) * 64 + lane;
      int rr = s >> 3, ch = s & 7;
      int gch = ch ^ (rr & 7);
      load_lds16(A + (size_t)(m0 + rr) * K + kt + gch * 8, (char*)As + (i * 4 + w) * 1024);
      load_lds16(B2 + (size_t)(n0 + rr) * K + kt + gch * 8, (char*)Bs + (i * 4 + w) * 1024);
    }
    __syncthreads();
    #pragma unroll
    for (int ks = 0; ks < 2; ++ks) {
      short8 af[4], bfr[4];
      #pragma unroll
      for (int a = 0; a < 4; ++a) {
        int rr = wm + a * 16 + lane16;
        int gg = ks * 4 + quad;
        af[a] = *(const short8*)(As + rr * 64 + (gg ^ (rr & 7)) * 8);
      }
      #pragma unroll
      for (int b = 0; b < 4; ++b) {
        int rr = wn + b * 16 + lane16;
        int gg = ks * 4 + quad;
        bfr[b] = *(const short8*)(Bs + rr * 64 + (gg ^ (rr & 7)) * 8);
      }
      #pragma unroll
      for (int a = 0; a < 4; ++a)
        #pragma unroll
        for (int b = 0; b < 4; ++b)
          acc[a][b] = __builtin_amdgcn_mfma_f32_16x16x32_bf16(af[a], bfr[b], acc[a][b], 0, 0, 0);
    }
  }
  #pragma unroll
  for (int a = 0; a < 4; ++a) {
    #pragma unroll
    for (int b = 0; b < 4; ++b) {
      int col = n0 + wn + b * 16 + lane16;
      float bv = bias ? bias[col] : 0.0f;
      #pragma unroll
      for (int rg = 0; rg < 4; ++rg) {
        int row = m0 + wm + a * 16 + quad * 4 + rg;
        float v = acc[a][b][rg] + bv;
        if (act) v = tanhf(v);
        C[(size_t)row * N + col] = __float2bfloat16(v);
      }
    }
  }
}

// ---------------------------------------------------------------- persistent LSTM scan (one layer, 2 cells)
// 256 blocks x 512 thr. Block: cell c, hidden slice hs=p*32, batch slice rb=r*16.
// Gates for step t: Xproj[t] (precomputed, incl. biases) + h(t-1) @ Whh^T.
//
// h exchange through the MALL (sc0 sc1). r0 structure (proven) with ONE change:
// the single flag word + 16 serialized atomicAdds is replaced by 16 parallel
// per-producer flag WORDS in one 64B line. Producer block (p,d): after its h
// stores drain (vmcnt(0)) and barrier [D], tid0 plain-stores flags[t][d][p]=1
// (sc0 sc1, no RMW -> the 16 producers publish in parallel instead of
// chaining RMWs). Consumer: lanes 0..15 of wave 0 each poll their own word
// (one exec-masked gather per round, <=64B per block per round — poll traffic
// class identical to r0's single-lane poll; the r1/r2 regressions came from
// 512-lane polling, which this does NOT reintroduce). s_sleep(1) backoff
// between poll rounds (~64cy, << 700cy MALL RTT).
// Barriers per step (t>0): [A] post-poll, [B] post-stage, [C] post-gbuf,
// [D] post-drain before publish — same count as r0.
__global__ __launch_bounds__(512) void lstm_scan(
    const b16* __restrict__ Xproj,   // [128*128][4096]
    const b16* __restrict__ Whh,     // [2][2048][512] bf16
    b16* __restrict__ hseq,          // [128*128][1024]
    int* __restrict__ flags) {       // [128][16][16] ints (64B line per (t,d))
  __shared__ __align__(16) b16 As[16 * 528];
  __shared__ __align__(16) float gbuf[8][16][16];
  const int tid = threadIdx.x;
  const int bid = blockIdx.x;
  const int p = bid >> 4, d = bid & 15;   // domain d = c*8 + r
  const int c = d >> 3, r = d & 7;
  const int rb = r * 16, hs = p * 32;
  const int w = tid >> 6, lane = tid & 63;
  const int quad = lane >> 4, lane16 = lane & 15;
  const int gate = w >> 1, half = w & 1;
  const int colbase = gate * 512 + hs + half * 16;

  // resident weight fragments: wave w owns 16 gate-columns, all K=512
  short8 bfrag[16];
  {
    const b16* wp = Whh + ((size_t)(c * 2048 + colbase + lane16)) * 512 + quad * 8;
    #pragma unroll
    for (int ks = 0; ks < 16; ++ks) bfrag[ks] = *(const short8*)(wp + ks * 32);
  }
  // cell-update ownership: threads 0..255, batch row rb+bloc, hidden pair hs+2*hp
  const int bloc = tid >> 4, hp = tid & 15;
  // staging ownership: row srow (16 rows), 32B chunk schunk
  const int srow = tid >> 5, schunk = tid & 31;
  float cs0 = 0.0f, cs1 = 0.0f;

  for (int t = 0; t < T_; ++t) {
    // prefetch Xproj gate dwords early (plain cached loads)
    unsigned xpr[4];
    if (tid < 256) {
      const unsigned* xb =
          (const unsigned*)(Xproj + ((size_t)t * 128 + rb + bloc) * 4096 + c * 2048 + hs + hp * 2);
      #pragma unroll
      for (int g4 = 0; g4 < 4; ++g4) xpr[g4] = xb[g4 * 256];
    }
    float4v acc0 = {0.f, 0.f, 0.f, 0.f}, acc1 = {0.f, 0.f, 0.f, 0.f};
    float4v acc2 = {0.f, 0.f, 0.f, 0.f}, acc3 = {0.f, 0.f, 0.f, 0.f};
    if (t > 0) {
      // lanes 0..15 of wave 0: poll per-producer words of group (t-1, d)
      if (tid < 16) {
        const int* fp = flags + (((t - 1) * 16 + d) << 4) + tid;
        int fv;
        while (true) {
          asm volatile("global_load_dword %0, %1, off sc0 sc1\n\t"
                       "s_waitcnt vmcnt(0)"
                       : "=v"(fv) : "v"(fp) : "memory");
          if (fv != 0) break;
          __builtin_amdgcn_s_sleep(1);
        }
      }
      __syncthreads();                                   // [A]
      // stage h(t-1)[rb..rb+16, cell c] -> LDS [16][528] via MALL (sc0 sc1)
      {
        const b16* g = hseq + ((size_t)(t - 1) * 128 + rb + srow) * 1024 + c * 512 + schunk * 16;
        uint4 v0, v1;
        asm volatile("global_load_dwordx4 %0, %2, off sc0 sc1\n\t"
                     "global_load_dwordx4 %1, %2, off offset:16 sc0 sc1"
                     : "=&v"(v0), "=&v"(v1) : "v"(g) : "memory");
        asm volatile("s_waitcnt vmcnt(0)" ::: "memory");
        *(uint4*)(As + srow * 528 + schunk * 16) = v0;
        *(uint4*)(As + srow * 528 + schunk * 16 + 8) = v1;
      }
      __syncthreads();                                   // [B]
      // 4 independent accumulation chains to break MFMA latency serialization
      #pragma unroll
      for (int ks = 0; ks < 16; ks += 4) {
        short8 a0 = *(const short8*)(As + lane16 * 528 + (ks + 0) * 32 + quad * 8);
        short8 a1 = *(const short8*)(As + lane16 * 528 + (ks + 1) * 32 + quad * 8);
        short8 a2 = *(const short8*)(As + lane16 * 528 + (ks + 2) * 32 + quad * 8);
        short8 a3 = *(const short8*)(As + lane16 * 528 + (ks + 3) * 32 + quad * 8);
        acc0 = __builtin_amdgcn_mfma_f32_16x16x32_bf16(a0, bfrag[ks + 0], acc0, 0, 0, 0);
        acc1 = __builtin_amdgcn_mfma_f32_16x16x32_bf16(a1, bfrag[ks + 1], acc1, 0, 0, 0);
        acc2 = __builtin_amdgcn_mfma_f32_16x16x32_bf16(a2, bfrag[ks + 2], acc2, 0, 0, 0);
        acc3 = __builtin_amdgcn_mfma_f32_16x16x32_bf16(a3, bfrag[ks + 3], acc3, 0, 0, 0);
      }
    }
    #pragma unroll
    for (int rg = 0; rg < 4; ++rg)
      gbuf[w][quad * 4 + rg][lane16] = acc0[rg] + acc1[rg] + acc2[rg] + acc3[rg];
    __syncthreads();                                     // [C]
    if (tid < 256) {  // cell update: 2 adjacent hidden units per thread
      const size_t xrow = (size_t)t * 128 + rb + bloc;
      const int hhalf = hp >> 3;          // (2*hp)>>4
      const int ci = 2 * (hp & 7);        // (2*hp)&15
      float g0[4], g1[4];
      #pragma unroll
      for (int g4 = 0; g4 < 4; ++g4) {
        float2 gv = *(const float2*)&gbuf[g4 * 2 + hhalf][bloc][ci];
        g0[g4] = gv.x + blo(xpr[g4]);
        g1[g4] = gv.y + bhi(xpr[g4]);
      }
      float i0 = sigm(g0[0]), f0 = sigm(g0[1]), gg0 = tanhf(g0[2]), o0 = sigm(g0[3]);
      float i1 = sigm(g1[0]), f1 = sigm(g1[1]), gg1 = tanhf(g1[2]), o1 = sigm(g1[3]);
      cs0 = f0 * cs0 + i0 * gg0;
      cs1 = f1 * cs1 + i1 * gg1;
      unsigned hv = pack2bf(o0 * tanhf(cs0), o1 * tanhf(cs1));
      unsigned* ha = (unsigned*)(hseq + xrow * 1024 + c * 512 + hs) + hp;
      asm volatile("global_store_dword %0, %1, off sc0 sc1" :: "v"(ha), "v"(hv) : "memory");
    }
    // drain this wave's h stores, then block-wide publish of flag word p
    asm volatile("s_waitcnt vmcnt(0)" ::: "memory");
    __syncthreads();                                     // [D]
    if (tid == 0) {
      int one = 1;
      const int* fq = flags + ((t * 16 + d) << 4) + p;
      asm volatile("global_store_dword %0, %1, off sc0 sc1" :: "v"(fq), "v"(one) : "memory");
    }
  }
}

// ---------------------------------------------------------------- build rep row [target | context | src_e | pad], write target fp32 out
__global__ void build_rep(const int* __restrict__ article, const int* __restrict__ positions,
                          const int* __restrict__ srcs, const float* __restrict__ E,
                          const float* __restrict__ src_emb, const b16* __restrict__ Xg,
                          const b16* __restrict__ h2seq, b16* __restrict__ rep,
                          float* __restrict__ out) {
  int b = blockIdx.x, tid = threadIdx.x;
  int pos = positions[b], sc = srcs[b];
  for (int k = tid; k < 2176; k += 256) {
    b16 v;
    if (k < 1024)      v = Xg[((size_t)pos * 128 + b) * 1024 + k];
    else if (k < 2048) v = h2seq[((size_t)127 * 128 + b) * 1024 + (k - 1024)];
    else if (k < 2148) v = __float2bfloat16(src_emb[sc * 100 + (k - 2048)]);
    else               v = __float2bfloat16(0.0f);
    rep[(size_t)b * 2176 + k] = v;
  }
  int tok = article[b * T_ + pos];
  for (int k = tid; k < 1024; k += 256)
    out[512 + b * 1024 + k] = E[(size_t)tok * 1024 + k];
}

// ---------------------------------------------------------------- logits + probs
__global__ void classifier(const b16* __restrict__ feat, const float* __restrict__ cW,
                           const float* __restrict__ cb, float* __restrict__ out) {
  __shared__ float red[256];
  int tid = threadIdx.x;
  int pairIdx = tid >> 3, jc = tid & 7;
  int bl = pairIdx >> 1, l = pairIdx & 1;
  int b = blockIdx.x * 16 + bl;
  int j0 = jc * 135, j1 = (j0 + 135 < 1074) ? j0 + 135 : 1074;
  float s = 0.f;
  for (int j = j0; j < j1; ++j)
    s += __bfloat162float(feat[(size_t)b * 1152 + j]) * cW[l * 1074 + j];
  red[tid] = s;
  __syncthreads();
  if (jc == 0) {
    float tot = 0.f;
    #pragma unroll
    for (int q = 0; q < 8; ++q) tot += red[pairIdx * 8 + q];
    tot += cb[l];
    out[b * 2 + l] = tot;
    out[256 + b * 2 + l] = 1.0f / (1.0f + __expf(-tot));
  }
}

// ----------------------------------------------------------------
extern "C" void kernel_launch(void* const* d_in, const int* in_sizes, int n_in,
                              void* d_out, int out_size, void* d_ws, size_t ws_size,
                              hipStream_t stream) {
  const int* article = (const int*)d_in[0];
  const int* positions = (const int*)d_in[1];
  const int* srcs = (const int*)d_in[2];
  const float* E = (const float*)d_in[3];
  const float* src_emb = (const float*)d_in[4];
  const float* Wih0f = (const float*)d_in[5];
  const float* Whh0f = (const float*)d_in[6];
  const float* bih0f = (const float*)d_in[7];
  const float* bhh0f = (const float*)d_in[8];
  const float* Wih0b = (const float*)d_in[9];
  const float* Whh0b = (const float*)d_in[10];
  const float* bih0b = (const float*)d_in[11];
  const float* bhh0b = (const float*)d_in[12];
  const float* Wih1f = (const float*)d_in[13];
  const float* Whh1f = (const float*)d_in[14];
  const float* bih1f = (const float*)d_in[15];
  const float* bhh1f = (const float*)d_in[16];
  const float* Wih1b = (const float*)d_in[17];
  const float* Whh1b = (const float*)d_in[18];
  const float* bih1b = (const float*)d_in[19];
  const float* bhh1b = (const float*)d_in[20];
  const float* dW = (const float*)d_in[21];
  const float* db = (const float*)d_in[22];
  const float* cW = (const float*)d_in[23];
  const float* cb = (const float*)d_in[24];

  char* ws = (char*)d_ws;
  size_t off = 0;
  auto carve = [&](size_t bytes) -> void* {
    void* p = ws + off;
    off += (bytes + 255) & ~(size_t)255;
    return p;
  };
  b16* Xg    = (b16*)carve((size_t)16384 * 1024 * 2);
  b16* h1seq = (b16*)carve((size_t)16384 * 1024 * 2);
  b16* h2seq = (b16*)carve((size_t)16384 * 1024 * 2);
  b16* Xproj = (b16*)carve((size_t)16384 * 4096 * 2);  // reused for layer0 and layer1
  b16* W0cat = (b16*)carve((size_t)4096 * 1024 * 2);
  b16* W1cat = (b16*)carve((size_t)4096 * 1024 * 2);
  b16* Whh0  = (b16*)carve((size_t)2 * 2048 * 512 * 2);
  b16* Whh1  = (b16*)carve((size_t)2 * 2048 * 512 * 2);
  b16* dWpad = (b16*)carve((size_t)1152 * 2176 * 2);
  b16* rep   = (b16*)carve((size_t)128 * 2176 * 2);
  b16* feat  = (b16*)carve((size_t)128 * 1152 * 2);
  float* bias0 = (float*)carve(4096 * 4);
  float* bias1 = (float*)carve(4096 * 4);
  float* dbpad = (float*)carve(1152 * 4);
  int* flags1 = (int*)carve(128 * 16 * 16 * 4);
  int* flags2 = (int*)carve(128 * 16 * 16 * 4);
  (void)ws_size; (void)in_sizes; (void)n_in; (void)out_size;

  hipMemsetAsync(flags1, 0, 2 * 128 * 16 * 16 * 4, stream);

  gather_x<<<16384, 256, 0, stream>>>(article, E, Xg);
  cvt_cat2<<<8192, 256, 0, stream>>>(Wih0f, Wih0b, W0cat, 2048, 1024, 4096 * 1024);
  cvt_cat2<<<8192, 256, 0, stream>>>(Wih1f, Wih1b, W1cat, 2048, 1024, 4096 * 1024);
  cvt_cat2<<<8192, 256, 0, stream>>>(Whh0f, Whh0b, Whh0, 2048, 512, 4096 * 512);
  cvt_cat2<<<8192, 256, 0, stream>>>(Whh1f, Whh1b, Whh1, 2048, 512, 4096 * 512);
  prep_bias<<<16, 256, 0, stream>>>(bih0f, bhh0f, bih0b, bhh0b, bias0);
  prep_bias<<<16, 256, 0, stream>>>(bih1f, bhh1f, bih1b, bhh1b, bias1);
  prep_dw<<<9792, 256, 0, stream>>>(dW, db, dWpad, dbpad);

  gemm_bt<<<dim3(32, 128), 256, 0, stream>>>(Xg, W0cat, Xproj, bias0, 16384, 4096, 1024, 0);
  lstm_scan<<<256, 512, 0, stream>>>(Xproj, Whh0, h1seq, flags1);
  gemm_bt<<<dim3(32, 128), 256, 0, stream>>>(h1seq, W1cat, Xproj, bias1, 16384, 4096, 1024, 0);
  lstm_scan<<<256, 512, 0, stream>>>(Xproj, Whh1, h2seq, flags2);

  build_rep<<<128, 256, 0, stream>>>(article, positions, srcs, E, src_emb, Xg, h2seq, rep,
                                     (float*)d_out);
  gemm_bt<<<dim3(9, 1), 256, 0, stream>>>(rep, dWpad, feat, dbpad, 128, 1152, 2176, 1);
  classifier<<<8, 256, 0, stream>>>(feat, cW, cb, (float*)d_out);
}

// Round 5
// 1384.094 us; speedup vs baseline: 1.8804x; 1.0788x over previous
//
#include <hip/hip_runtime.h>
#include <hip/hip_bf16.h>

typedef short short8 __attribute__((ext_vector_type(8)));
typedef float float4v __attribute__((ext_vector_type(4)));
typedef __hip_bfloat16 b16;
typedef unsigned short ushort_t;

#define T_ 128

__device__ __forceinline__ float sigm(float x) { return 1.0f / (1.0f + __expf(-x)); }
__device__ __forceinline__ unsigned pack2bf(float a, float b) {
  b16 ha = __float2bfloat16(a), hb = __float2bfloat16(b);
  return (unsigned)*(ushort_t*)&ha | ((unsigned)*(ushort_t*)&hb << 16);
}

__device__ __forceinline__ void load_lds16(const void* g, void* l) {
  __builtin_amdgcn_global_load_lds((const __attribute__((address_space(1))) void*)g,
                                   (__attribute__((address_space(3))) void*)l, 16, 0, 0);
}

// ---------------------------------------------------------------- gather E rows -> bf16, t-major rows (r = t*128 + b)
__global__ void gather_x(const int* __restrict__ article, const float* __restrict__ E,
                         b16* __restrict__ Xg) {
  int r = blockIdx.x;
  int b = r & 127, t = r >> 7;
  int tok = article[b * T_ + t];
  const float4* src = (const float4*)(E + (size_t)tok * 1024);
  float4 v = src[threadIdx.x];
  b16* dst = Xg + (size_t)r * 1024 + threadIdx.x * 4;
  dst[0] = __float2bfloat16(v.x);
  dst[1] = __float2bfloat16(v.y);
  dst[2] = __float2bfloat16(v.z);
  dst[3] = __float2bfloat16(v.w);
}

// ---------------------------------------------------------------- stack two fp32 [rows_each x k] into bf16 [2*rows_each x k]
__global__ void cvt_cat2(const float* __restrict__ s0, const float* __restrict__ s1,
                         b16* __restrict__ out, int rows_each, int k, int total) {
  for (int idx = blockIdx.x * 256 + threadIdx.x; idx < total; idx += gridDim.x * 256) {
    int row = idx / k, col = idx - row * k;
    float v = (row < rows_each) ? s0[(size_t)row * k + col]
                                : s1[(size_t)(row - rows_each) * k + col];
    out[idx] = __float2bfloat16(v);
  }
}

// ---------------------------------------------------------------- bias0[j] = (bih+bhh) per cell, j in [0,4096)
__global__ void prep_bias(const float* bf1, const float* bf2, const float* bb1,
                          const float* bb2, float* out) {
  int j = blockIdx.x * 256 + threadIdx.x;
  int c = j >> 11, jj = j & 2047;
  out[j] = c ? (bb1[jj] + bb2[jj]) : (bf1[jj] + bf2[jj]);
}

// ---------------------------------------------------------------- pad dW [1074x2148] -> bf16 [1152x2176], db -> dbpad[1152]
__global__ void prep_dw(const float* __restrict__ dW, const float* __restrict__ db,
                        b16* __restrict__ dWpad, float* __restrict__ dbpad) {
  int idx = blockIdx.x * 256 + threadIdx.x;  // grid sized to exactly 1152*2176
  int r = idx / 2176, k = idx - r * 2176;
  float v = (r < 1074 && k < 2148) ? dW[(size_t)r * 2148 + k] : 0.0f;
  dWpad[idx] = __float2bfloat16(v);
  if (idx < 1152) dbpad[idx] = (idx < 1074) ? db[idx] : 0.0f;
}

// ---------------------------------------------------------------- bf16 GEMM: C[MxN] = A[MxK] @ B2[NxK]^T + bias (opt tanh)
// 128x128 tile, BK=64, global_load_lds(16B) staging with XOR chunk swizzle.
// Used only for the small dW projection now.
__global__ __launch_bounds__(256) void gemm_bt(
    const b16* __restrict__ A, const b16* __restrict__ B2, b16* __restrict__ C,
    const float* __restrict__ bias, int M, int N, int K, int act) {
  __shared__ __align__(16) b16 As[128 * 64];
  __shared__ __align__(16) b16 Bs[128 * 64];
  const int tid = threadIdx.x;
  const int w = tid >> 6, lane = tid & 63;
  const int quad = lane >> 4, lane16 = lane & 15;
  const int m0 = blockIdx.y * 128, n0 = blockIdx.x * 128;
  const int wm = (w >> 1) * 64, wn = (w & 1) * 64;
  float4v acc[4][4] = {};
  for (int kt = 0; kt < K; kt += 64) {
    __syncthreads();
    #pragma unroll
    for (int i = 0; i < 4; ++i) {
      int s = (i * 4 + w) * 64 + lane;
      int rr = s >> 3, ch = s & 7;
      int gch = ch ^ (rr & 7);
      load_lds16(A + (size_t)(m0 + rr) * K + kt + gch * 8, (char*)As + (i * 4 + w) * 1024);
      load_lds16(B2 + (size_t)(n0 + rr) * K + kt + gch * 8, (char*)Bs + (i * 4 + w) * 1024);
    }
    __syncthreads();
    #pragma unroll
    for (int ks = 0; ks < 2; ++ks) {
      short8 af[4], bfr[4];
      #pragma unroll
      for (int a = 0; a < 4; ++a) {
        int rr = wm + a * 16 + lane16;
        int gg = ks * 4 + quad;
        af[a] = *(const short8*)(As + rr * 64 + (gg ^ (rr & 7)) * 8);
      }
      #pragma unroll
      for (int b = 0; b < 4; ++b) {
        int rr = wn + b * 16 + lane16;
        int gg = ks * 4 + quad;
        bfr[b] = *(const short8*)(Bs + rr * 64 + (gg ^ (rr & 7)) * 8);
      }
      #pragma unroll
      for (int a = 0; a < 4; ++a)
        #pragma unroll
        for (int b = 0; b < 4; ++b)
          acc[a][b] = __builtin_amdgcn_mfma_f32_16x16x32_bf16(af[a], bfr[b], acc[a][b], 0, 0, 0);
    }
  }
  #pragma unroll
  for (int a = 0; a < 4; ++a) {
    #pragma unroll
    for (int b = 0; b < 4; ++b) {
      int col = n0 + wn + b * 16 + lane16;
      float bv = bias ? bias[col] : 0.0f;
      #pragma unroll
      for (int rg = 0; rg < 4; ++rg) {
        int row = m0 + wm + a * 16 + quad * 4 + rg;
        float v = acc[a][b][rg] + bv;
        if (act) v = tanhf(v);
        C[(size_t)row * N + col] = __float2bfloat16(v);
      }
    }
  }
}

// ---------------------------------------------------------------- fused persistent LSTM layer: input-proj GEMM + scan
// 256 blocks x 512 thr, launched once per layer. Block: cell c, hidden slice
// hs=p*32, batch slice rb=r*16. Gates for step t computed IN-BLOCK:
//   g = x(t) @ Wih_slice^T  (K=1024, weights resident: bin[32])
//     + h(t-1) @ Whh_slice^T (K=512, resident: bhh[16])
//     + bias (registers, added at cell update)
// This folds the former 330us Xproj GEMM into the scan's latency bubbles
// (scan was 8% MfmaUtil): +32 MFMA/wave/step + a 32KB LDS x-tile staged via
// global_load_lds (plain loads -> L2-cached; 16 blocks reuse each row).
// Sync structure is byte-identical to the proven r0 scan (335us): single
// counter word per (t,d), tid0 tight poll, 4 barriers/step, h exchange via
// MALL (sc0 sc1). VGPR budget: bin 128 + bhh 64 + ~40 working, capped by
// launch_bounds(512,2) -> 256/wave, 1 WG/CU (8 waves = 2/SIMD).
__global__ __launch_bounds__(512, 2) void lstm_scan_f(
    const b16* __restrict__ xin,    // [128*128][1024] t-major input rows
    const b16* __restrict__ Wcat,   // [4096][1024] (cell-major gate rows)
    const b16* __restrict__ Whh,    // [2][2048][512]
    const float* __restrict__ bias, // [4096] = bih+bhh, cell-major
    b16* __restrict__ hout,         // [128*128][1024]
    int* __restrict__ flags) {      // [128][16] counters, stride-16 ints
  __shared__ __align__(16) b16 Xs[16 * 1032];   // x tile, +8 pad/row
  __shared__ __align__(16) b16 Hs[16 * 528];    // h tile
  __shared__ __align__(16) float gbuf[8][16][16];
  const int tid = threadIdx.x;
  const int bid = blockIdx.x;
  const int p = bid >> 4, d = bid & 15;   // domain d = c*8 + r
  const int c = d >> 3, r = d & 7;
  const int rb = r * 16, hs = p * 32;
  const int w = tid >> 6, lane = tid & 63;
  const int quad = lane >> 4, lane16 = lane & 15;
  const int gate = w >> 1, half = w & 1;
  const int colbase = gate * 512 + hs + half * 16;

  // resident weight fragments: wave w owns 16 gate-columns
  short8 bin[32];   // input projection, K=1024
  {
    const b16* wp = Wcat + ((size_t)(c * 2048 + colbase + lane16)) * 1024 + quad * 8;
    #pragma unroll
    for (int ks = 0; ks < 32; ++ks) bin[ks] = *(const short8*)(wp + ks * 32);
  }
  short8 bhh[16];   // recurrent, K=512
  {
    const b16* wp = Whh + ((size_t)(c * 2048 + colbase + lane16)) * 512 + quad * 8;
    #pragma unroll
    for (int ks = 0; ks < 16; ++ks) bhh[ks] = *(const short8*)(wp + ks * 32);
  }
  // cell-update ownership: threads 0..255, batch row rb+bloc, hidden pair hs+2*hp
  const int bloc = tid >> 4, hp = tid & 15;
  // staging ownership for Hs: row srow (16 rows), 32B chunk schunk
  const int srow = tid >> 5, schunk = tid & 31;
  // bias registers for the cell update (valid for tid<256; harmless otherwise)
  float bs0[4], bs1[4];
  #pragma unroll
  for (int g4 = 0; g4 < 4; ++g4) {
    bs0[g4] = bias[c * 2048 + g4 * 512 + hs + 2 * hp];
    bs1[g4] = bias[c * 2048 + g4 * 512 + hs + 2 * hp + 1];
  }
  float cs0 = 0.0f, cs1 = 0.0f;

  for (int t = 0; t < T_; ++t) {
    if (t > 0 && tid == 0) {   // r0-proven single-word tight poll
      const int* fp = flags + ((t - 1) * 16 + d) * 16;
      while (__hip_atomic_load(fp, __ATOMIC_RELAXED, __HIP_MEMORY_SCOPE_AGENT) < 16) {}
    }
    if (t > 0) __syncthreads();                          // [A]
    // stage x(t)[rb..rb+16, 0..1024) -> Xs via global_load_lds (plain/L2).
    // 32 wave-loads of 1024B: idx = i*8+w -> (row, halfrow); dest is
    // wave-uniform base + lane*16 (padded row stride 2064B, 16B-aligned).
    #pragma unroll
    for (int i = 0; i < 4; ++i) {
      int idx = i * 8 + w;
      int row = idx >> 1, hrow = idx & 1;
      load_lds16(xin + ((size_t)t * 128 + rb + row) * 1024 + hrow * 512 + lane * 8,
                 (char*)Xs + row * 2064 + hrow * 1024);
    }
    if (t > 0) {
      // stage h(t-1)[rb..rb+16, cell c] -> Hs via MALL (sc0 sc1), r0 pattern
      const b16* g = hout + ((size_t)(t - 1) * 128 + rb + srow) * 1024 + c * 512 + schunk * 16;
      uint4 v0, v1;
      asm volatile("global_load_dwordx4 %0, %2, off sc0 sc1\n\t"
                   "global_load_dwordx4 %1, %2, off offset:16 sc0 sc1"
                   : "=&v"(v0), "=&v"(v1) : "v"(g) : "memory");
      asm volatile("s_waitcnt vmcnt(0)" ::: "memory");
      *(uint4*)(Hs + srow * 528 + schunk * 16) = v0;
      *(uint4*)(Hs + srow * 528 + schunk * 16 + 8) = v1;
    }
    __syncthreads();                                     // [B] (drains lds-loads)
    // gate accumulation: 32 input-proj MFMA + 16 recurrent MFMA, 2 chains
    float4v acc0 = {0.f, 0.f, 0.f, 0.f}, acc1 = {0.f, 0.f, 0.f, 0.f};
    #pragma unroll
    for (int ks = 0; ks < 32; ks += 2) {
      short8 a0 = *(const short8*)(Xs + lane16 * 1032 + ks * 32 + quad * 8);
      short8 a1 = *(const short8*)(Xs + lane16 * 1032 + (ks + 1) * 32 + quad * 8);
      acc0 = __builtin_amdgcn_mfma_f32_16x16x32_bf16(a0, bin[ks], acc0, 0, 0, 0);
      acc1 = __builtin_amdgcn_mfma_f32_16x16x32_bf16(a1, bin[ks + 1], acc1, 0, 0, 0);
    }
    if (t > 0) {
      #pragma unroll
      for (int ks = 0; ks < 16; ks += 2) {
        short8 a0 = *(const short8*)(Hs + lane16 * 528 + ks * 32 + quad * 8);
        short8 a1 = *(const short8*)(Hs + lane16 * 528 + (ks + 1) * 32 + quad * 8);
        acc0 = __builtin_amdgcn_mfma_f32_16x16x32_bf16(a0, bhh[ks], acc0, 0, 0, 0);
        acc1 = __builtin_amdgcn_mfma_f32_16x16x32_bf16(a1, bhh[ks + 1], acc1, 0, 0, 0);
      }
    }
    #pragma unroll
    for (int rg = 0; rg < 4; ++rg)
      gbuf[w][quad * 4 + rg][lane16] = acc0[rg] + acc1[rg];
    __syncthreads();                                     // [C]
    if (tid < 256) {  // cell update: 2 adjacent hidden units per thread
      const size_t xrow = (size_t)t * 128 + rb + bloc;
      const int hhalf = hp >> 3;
      const int ci = 2 * (hp & 7);
      float g0[4], g1[4];
      #pragma unroll
      for (int g4 = 0; g4 < 4; ++g4) {
        float2 gv = *(const float2*)&gbuf[g4 * 2 + hhalf][bloc][ci];
        g0[g4] = gv.x + bs0[g4];
        g1[g4] = gv.y + bs1[g4];
      }
      float i0 = sigm(g0[0]), f0 = sigm(g0[1]), gg0 = tanhf(g0[2]), o0 = sigm(g0[3]);
      float i1 = sigm(g1[0]), f1 = sigm(g1[1]), gg1 = tanhf(g1[2]), o1 = sigm(g1[3]);
      cs0 = f0 * cs0 + i0 * gg0;
      cs1 = f1 * cs1 + i1 * gg1;
      unsigned hv = pack2bf(o0 * tanhf(cs0), o1 * tanhf(cs1));
      unsigned* ha = (unsigned*)(hout + xrow * 1024 + c * 512 + hs) + hp;
      asm volatile("global_store_dword %0, %1, off sc0 sc1" :: "v"(ha), "v"(hv) : "memory");
    }
    asm volatile("s_waitcnt vmcnt(0)" ::: "memory");
    __syncthreads();                                     // [D]
    if (tid == 0)
      __hip_atomic_fetch_add(&flags[(t * 16 + d) * 16], 1, __ATOMIC_RELAXED,
                             __HIP_MEMORY_SCOPE_AGENT);
  }
}

// ---------------------------------------------------------------- build rep row [target | context | src_e | pad], write target fp32 out
__global__ void build_rep(const int* __restrict__ article, const int* __restrict__ positions,
                          const int* __restrict__ srcs, const float* __restrict__ E,
                          const float* __restrict__ src_emb, const b16* __restrict__ Xg,
                          const b16* __restrict__ h2seq, b16* __restrict__ rep,
                          float* __restrict__ out) {
  int b = blockIdx.x, tid = threadIdx.x;
  int pos = positions[b], sc = srcs[b];
  for (int k = tid; k < 2176; k += 256) {
    b16 v;
    if (k < 1024)      v = Xg[((size_t)pos * 128 + b) * 1024 + k];
    else if (k < 2048) v = h2seq[((size_t)127 * 128 + b) * 1024 + (k - 1024)];
    else if (k < 2148) v = __float2bfloat16(src_emb[sc * 100 + (k - 2048)]);
    else               v = __float2bfloat16(0.0f);
    rep[(size_t)b * 2176 + k] = v;
  }
  int tok = article[b * T_ + pos];
  for (int k = tid; k < 1024; k += 256)
    out[512 + b * 1024 + k] = E[(size_t)tok * 1024 + k];
}

// ---------------------------------------------------------------- logits + probs
__global__ void classifier(const b16* __restrict__ feat, const float* __restrict__ cW,
                           const float* __restrict__ cb, float* __restrict__ out) {
  __shared__ float red[256];
  int tid = threadIdx.x;
  int pairIdx = tid >> 3, jc = tid & 7;
  int bl = pairIdx >> 1, l = pairIdx & 1;
  int b = blockIdx.x * 16 + bl;
  int j0 = jc * 135, j1 = (j0 + 135 < 1074) ? j0 + 135 : 1074;
  float s = 0.f;
  for (int j = j0; j < j1; ++j)
    s += __bfloat162float(feat[(size_t)b * 1152 + j]) * cW[l * 1074 + j];
  red[tid] = s;
  __syncthreads();
  if (jc == 0) {
    float tot = 0.f;
    #pragma unroll
    for (int q = 0; q < 8; ++q) tot += red[pairIdx * 8 + q];
    tot += cb[l];
    out[b * 2 + l] = tot;
    out[256 + b * 2 + l] = 1.0f / (1.0f + __expf(-tot));
  }
}

// ----------------------------------------------------------------
extern "C" void kernel_launch(void* const* d_in, const int* in_sizes, int n_in,
                              void* d_out, int out_size, void* d_ws, size_t ws_size,
                              hipStream_t stream) {
  const int* article = (const int*)d_in[0];
  const int* positions = (const int*)d_in[1];
  const int* srcs = (const int*)d_in[2];
  const float* E = (const float*)d_in[3];
  const float* src_emb = (const float*)d_in[4];
  const float* Wih0f = (const float*)d_in[5];
  const float* Whh0f = (const float*)d_in[6];
  const float* bih0f = (const float*)d_in[7];
  const float* bhh0f = (const float*)d_in[8];
  const float* Wih0b = (const float*)d_in[9];
  const float* Whh0b = (const float*)d_in[10];
  const float* bih0b = (const float*)d_in[11];
  const float* bhh0b = (const float*)d_in[12];
  const float* Wih1f = (const float*)d_in[13];
  const float* Whh1f = (const float*)d_in[14];
  const float* bih1f = (const float*)d_in[15];
  const float* bhh1f = (const float*)d_in[16];
  const float* Wih1b = (const float*)d_in[17];
  const float* Whh1b = (const float*)d_in[18];
  const float* bih1b = (const float*)d_in[19];
  const float* bhh1b = (const float*)d_in[20];
  const float* dW = (const float*)d_in[21];
  const float* db = (const float*)d_in[22];
  const float* cW = (const float*)d_in[23];
  const float* cb = (const float*)d_in[24];

  char* ws = (char*)d_ws;
  size_t off = 0;
  auto carve = [&](size_t bytes) -> void* {
    void* p = ws + off;
    off += (bytes + 255) & ~(size_t)255;
    return p;
  };
  b16* Xg    = (b16*)carve((size_t)16384 * 1024 * 2);
  b16* h1seq = (b16*)carve((size_t)16384 * 1024 * 2);
  b16* h2seq = (b16*)carve((size_t)16384 * 1024 * 2);
  b16* W0cat = (b16*)carve((size_t)4096 * 1024 * 2);
  b16* W1cat = (b16*)carve((size_t)4096 * 1024 * 2);
  b16* Whh0  = (b16*)carve((size_t)2 * 2048 * 512 * 2);
  b16* Whh1  = (b16*)carve((size_t)2 * 2048 * 512 * 2);
  b16* dWpad = (b16*)carve((size_t)1152 * 2176 * 2);
  b16* rep   = (b16*)carve((size_t)128 * 2176 * 2);
  b16* feat  = (b16*)carve((size_t)128 * 1152 * 2);
  float* bias0 = (float*)carve(4096 * 4);
  float* bias1 = (float*)carve(4096 * 4);
  float* dbpad = (float*)carve(1152 * 4);
  int* flags1 = (int*)carve(128 * 16 * 16 * 4);
  int* flags2 = (int*)carve(128 * 16 * 16 * 4);
  (void)ws_size; (void)in_sizes; (void)n_in; (void)out_size;

  hipMemsetAsync(flags1, 0, 2 * 128 * 16 * 16 * 4, stream);

  gather_x<<<16384, 256, 0, stream>>>(article, E, Xg);
  cvt_cat2<<<8192, 256, 0, stream>>>(Wih0f, Wih0b, W0cat, 2048, 1024, 4096 * 1024);
  cvt_cat2<<<8192, 256, 0, stream>>>(Wih1f, Wih1b, W1cat, 2048, 1024, 4096 * 1024);
  cvt_cat2<<<8192, 256, 0, stream>>>(Whh0f, Whh0b, Whh0, 2048, 512, 4096 * 512);
  cvt_cat2<<<8192, 256, 0, stream>>>(Whh1f, Whh1b, Whh1, 2048, 512, 4096 * 512);
  prep_bias<<<16, 256, 0, stream>>>(bih0f, bhh0f, bih0b, bhh0b, bias0);
  prep_bias<<<16, 256, 0, stream>>>(bih1f, bhh1f, bih1b, bhh1b, bias1);
  prep_dw<<<9792, 256, 0, stream>>>(dW, db, dWpad, dbpad);

  // fused input-proj + scan, one launch per layer (GEMMs folded in)
  lstm_scan_f<<<256, 512, 0, stream>>>(Xg, W0cat, Whh0, bias0, h1seq, flags1);
  lstm_scan_f<<<256, 512, 0, stream>>>(h1seq, W1cat, Whh1, bias1, h2seq, flags2);

  build_rep<<<128, 256, 0, stream>>>(article, positions, srcs, E, src_emb, Xg, h2seq, rep,
                                     (float*)d_out);
  gemm_bt<<<dim3(9, 1), 256, 0, stream>>>(rep, dWpad, feat, dbpad, 128, 1152, 2176, 1);
  classifier<<<8, 256, 0, stream>>>(feat, cW, cb, (float*)d_out);
}

// Round 6
// 1289.204 us; speedup vs baseline: 2.0188x; 1.0736x over previous
//
#include <hip/hip_runtime.h>
#include <hip/hip_bf16.h>

typedef short short8 __attribute__((ext_vector_type(8)));
typedef float float4v __attribute__((ext_vector_type(4)));
typedef __hip_bfloat16 b16;
typedef unsigned short ushort_t;

#define T_ 128

__device__ __forceinline__ float sigm(float x) { return 1.0f / (1.0f + __expf(-x)); }
__device__ __forceinline__ unsigned pack2bf(float a, float b) {
  b16 ha = __float2bfloat16(a), hb = __float2bfloat16(b);
  return (unsigned)*(ushort_t*)&ha | ((unsigned)*(ushort_t*)&hb << 16);
}

__device__ __forceinline__ void load_lds16(const void* g, void* l) {
  __builtin_amdgcn_global_load_lds((const __attribute__((address_space(1))) void*)g,
                                   (__attribute__((address_space(3))) void*)l, 16, 0, 0);
}

// ---------------------------------------------------------------- gather E rows -> bf16, t-major rows (r = t*128 + b)
__global__ void gather_x(const int* __restrict__ article, const float* __restrict__ E,
                         b16* __restrict__ Xg) {
  int r = blockIdx.x;
  int b = r & 127, t = r >> 7;
  int tok = article[b * T_ + t];
  const float4* src = (const float4*)(E + (size_t)tok * 1024);
  float4 v = src[threadIdx.x];
  b16* dst = Xg + (size_t)r * 1024 + threadIdx.x * 4;
  dst[0] = __float2bfloat16(v.x);
  dst[1] = __float2bfloat16(v.y);
  dst[2] = __float2bfloat16(v.z);
  dst[3] = __float2bfloat16(v.w);
}

// ---------------------------------------------------------------- stack two fp32 [rows_each x k] into bf16 [2*rows_each x k]
__global__ void cvt_cat2(const float* __restrict__ s0, const float* __restrict__ s1,
                         b16* __restrict__ out, int rows_each, int k, int total) {
  for (int idx = blockIdx.x * 256 + threadIdx.x; idx < total; idx += gridDim.x * 256) {
    int row = idx / k, col = idx - row * k;
    float v = (row < rows_each) ? s0[(size_t)row * k + col]
                                : s1[(size_t)(row - rows_each) * k + col];
    out[idx] = __float2bfloat16(v);
  }
}

// ---------------------------------------------------------------- bias0[j] = (bih+bhh) per cell, j in [0,4096)
__global__ void prep_bias(const float* bf1, const float* bf2, const float* bb1,
                          const float* bb2, float* out) {
  int j = blockIdx.x * 256 + threadIdx.x;
  int c = j >> 11, jj = j & 2047;
  out[j] = c ? (bb1[jj] + bb2[jj]) : (bf1[jj] + bf2[jj]);
}

// ---------------------------------------------------------------- pad dW [1074x2148] -> bf16 [1152x2176], db -> dbpad[1152]
__global__ void prep_dw(const float* __restrict__ dW, const float* __restrict__ db,
                        b16* __restrict__ dWpad, float* __restrict__ dbpad) {
  int idx = blockIdx.x * 256 + threadIdx.x;  // grid sized to exactly 1152*2176
  int r = idx / 2176, k = idx - r * 2176;
  float v = (r < 1074 && k < 2148) ? dW[(size_t)r * 2148 + k] : 0.0f;
  dWpad[idx] = __float2bfloat16(v);
  if (idx < 1152) dbpad[idx] = (idx < 1074) ? db[idx] : 0.0f;
}

// ---------------------------------------------------------------- bf16 GEMM: C[MxN] = A[MxK] @ B2[NxK]^T + bias (opt tanh)
// 128x128 tile, BK=64, global_load_lds(16B) staging with XOR chunk swizzle.
// Used only for the small dW projection now.
__global__ __launch_bounds__(256) void gemm_bt(
    const b16* __restrict__ A, const b16* __restrict__ B2, b16* __restrict__ C,
    const float* __restrict__ bias, int M, int N, int K, int act) {
  __shared__ __align__(16) b16 As[128 * 64];
  __shared__ __align__(16) b16 Bs[128 * 64];
  const int tid = threadIdx.x;
  const int w = tid >> 6, lane = tid & 63;
  const int quad = lane >> 4, lane16 = lane & 15;
  const int m0 = blockIdx.y * 128, n0 = blockIdx.x * 128;
  const int wm = (w >> 1) * 64, wn = (w & 1) * 64;
  float4v acc[4][4] = {};
  for (int kt = 0; kt < K; kt += 64) {
    __syncthreads();
    #pragma unroll
    for (int i = 0; i < 4; ++i) {
      int s = (i * 4 + w) * 64 + lane;
      int rr = s >> 3, ch = s & 7;
      int gch = ch ^ (rr & 7);
      load_lds16(A + (size_t)(m0 + rr) * K + kt + gch * 8, (char*)As + (i * 4 + w) * 1024);
      load_lds16(B2 + (size_t)(n0 + rr) * K + kt + gch * 8, (char*)Bs + (i * 4 + w) * 1024);
    }
    __syncthreads();
    #pragma unroll
    for (int ks = 0; ks < 2; ++ks) {
      short8 af[4], bfr[4];
      #pragma unroll
      for (int a = 0; a < 4; ++a) {
        int rr = wm + a * 16 + lane16;
        int gg = ks * 4 + quad;
        af[a] = *(const short8*)(As + rr * 64 + (gg ^ (rr & 7)) * 8);
      }
      #pragma unroll
      for (int b = 0; b < 4; ++b) {
        int rr = wn + b * 16 + lane16;
        int gg = ks * 4 + quad;
        bfr[b] = *(const short8*)(Bs + rr * 64 + (gg ^ (rr & 7)) * 8);
      }
      #pragma unroll
      for (int a = 0; a < 4; ++a)
        #pragma unroll
        for (int b = 0; b < 4; ++b)
          acc[a][b] = __builtin_amdgcn_mfma_f32_16x16x32_bf16(af[a], bfr[b], acc[a][b], 0, 0, 0);
    }
  }
  #pragma unroll
  for (int a = 0; a < 4; ++a) {
    #pragma unroll
    for (int b = 0; b < 4; ++b) {
      int col = n0 + wn + b * 16 + lane16;
      float bv = bias ? bias[col] : 0.0f;
      #pragma unroll
      for (int rg = 0; rg < 4; ++rg) {
        int row = m0 + wm + a * 16 + quad * 4 + rg;
        float v = acc[a][b][rg] + bv;
        if (act) v = tanhf(v);
        C[(size_t)row * N + col] = __float2bfloat16(v);
      }
    }
  }
}

// ---------------------------------------------------------------- fused persistent LSTM layer: input-proj GEMM + scan
// 256 blocks x 512 thr, one launch per layer. Block: cell c, hidden slice
// hs=p*32, batch slice rb=r*16. Gates: g = x(t)@Wih^T (resident bin[32])
// + h(t-1)@Whh^T (resident bhh[16]) + bias (regs at cell update).
//
// r6 restructure vs r5: the X-projection has NO dependence on h(t-1), so it
// runs at the TOP of each iteration, BEFORE the poll — its 32 MFMA + 32
// ds_read_b128 (and their bank conflicts) execute inside the producer-wait
// window instead of extending the critical chain. x(t+1) is staged between
// [A] and [B] (all waves' Xs(t) reads complete before [A]; the loads drain
// at [B] alongside the H MALL loads, whose ~700cy RTT hides the L2-hot X).
// Critical chain per step is exactly the proven r0 scan:
//   publish(t-1) -> poll -> [A] -> H-stage -> [B] -> 16 H-MFMA -> gbuf ->
//   [C] -> cell -> h-store -> drain -> [D] -> publish(t).
// Sync protocol byte-identical to r0: single counter word per (t,d), tid0
// tight poll, 4 barriers/step, h exchange via MALL (sc0 sc1).
__global__ __launch_bounds__(512, 2) void lstm_scan_f(
    const b16* __restrict__ xin,    // [128*128][1024] t-major input rows
    const b16* __restrict__ Wcat,   // [4096][1024] (cell-major gate rows)
    const b16* __restrict__ Whh,    // [2][2048][512]
    const float* __restrict__ bias, // [4096] = bih+bhh, cell-major
    b16* __restrict__ hout,         // [128*128][1024]
    int* __restrict__ flags) {      // [128][16] counters, stride-16 ints
  __shared__ __align__(16) b16 Xs[16 * 1032];   // x tile, +8 pad/row
  __shared__ __align__(16) b16 Hs[16 * 528];    // h tile
  __shared__ __align__(16) float gbuf[8][16][16];
  const int tid = threadIdx.x;
  const int bid = blockIdx.x;
  const int p = bid >> 4, d = bid & 15;   // domain d = c*8 + r
  const int c = d >> 3, r = d & 7;
  const int rb = r * 16, hs = p * 32;
  const int w = tid >> 6, lane = tid & 63;
  const int quad = lane >> 4, lane16 = lane & 15;
  const int gate = w >> 1, half = w & 1;
  const int colbase = gate * 512 + hs + half * 16;

  // resident weight fragments: wave w owns 16 gate-columns
  short8 bin[32];   // input projection, K=1024
  {
    const b16* wp = Wcat + ((size_t)(c * 2048 + colbase + lane16)) * 1024 + quad * 8;
    #pragma unroll
    for (int ks = 0; ks < 32; ++ks) bin[ks] = *(const short8*)(wp + ks * 32);
  }
  short8 bhh[16];   // recurrent, K=512
  {
    const b16* wp = Whh + ((size_t)(c * 2048 + colbase + lane16)) * 512 + quad * 8;
    #pragma unroll
    for (int ks = 0; ks < 16; ++ks) bhh[ks] = *(const short8*)(wp + ks * 32);
  }
  // cell-update ownership: threads 0..255, batch row rb+bloc, hidden pair hs+2*hp
  const int bloc = tid >> 4, hp = tid & 15;
  // staging ownership for Hs: row srow (16 rows), 32B chunk schunk
  const int srow = tid >> 5, schunk = tid & 31;
  // bias registers for the cell update (valid for tid<256; harmless otherwise)
  float bs0[4], bs1[4];
  #pragma unroll
  for (int g4 = 0; g4 < 4; ++g4) {
    bs0[g4] = bias[c * 2048 + g4 * 512 + hs + 2 * hp];
    bs1[g4] = bias[c * 2048 + g4 * 512 + hs + 2 * hp + 1];
  }
  float cs0 = 0.0f, cs1 = 0.0f;

  // prologue: stage x(0); barrier drains each wave's own global_load_lds
  #pragma unroll
  for (int i = 0; i < 4; ++i) {
    int idx = i * 8 + w;
    int row = idx >> 1, hrow = idx & 1;
    load_lds16(xin + ((size_t)(rb + row)) * 1024 + hrow * 512 + lane * 8,
               (char*)Xs + row * 2064 + hrow * 1024);
  }
  __syncthreads();

  for (int t = 0; t < T_; ++t) {
    // ---- X-projection FIRST: independent of h(t-1), overlaps the poll ----
    float4v acc0 = {0.f, 0.f, 0.f, 0.f}, acc1 = {0.f, 0.f, 0.f, 0.f};
    #pragma unroll
    for (int ks = 0; ks < 32; ks += 2) {
      short8 a0 = *(const short8*)(Xs + lane16 * 1032 + ks * 32 + quad * 8);
      short8 a1 = *(const short8*)(Xs + lane16 * 1032 + (ks + 1) * 32 + quad * 8);
      acc0 = __builtin_amdgcn_mfma_f32_16x16x32_bf16(a0, bin[ks], acc0, 0, 0, 0);
      acc1 = __builtin_amdgcn_mfma_f32_16x16x32_bf16(a1, bin[ks + 1], acc1, 0, 0, 0);
    }
    if (t > 0 && tid == 0) {   // r0-proven single-word tight poll
      const int* fp = flags + ((t - 1) * 16 + d) * 16;
      while (__hip_atomic_load(fp, __ATOMIC_RELAXED, __HIP_MEMORY_SCOPE_AGENT) < 16) {}
    }
    __syncthreads();                                     // [A] (Xs reads done)
    // stage x(t+1) -> Xs (overwrite safe: all reads completed before [A];
    // drains at [B]'s vmcnt(0), hidden under the H MALL RTT)
    if (t + 1 < T_) {
      #pragma unroll
      for (int i = 0; i < 4; ++i) {
        int idx = i * 8 + w;
        int row = idx >> 1, hrow = idx & 1;
        load_lds16(xin + ((size_t)(t + 1) * 128 + rb + row) * 1024 + hrow * 512 + lane * 8,
                   (char*)Xs + row * 2064 + hrow * 1024);
      }
    }
    if (t > 0) {
      // stage h(t-1)[rb..rb+16, cell c] -> Hs via MALL (sc0 sc1), r0 pattern
      const b16* g = hout + ((size_t)(t - 1) * 128 + rb + srow) * 1024 + c * 512 + schunk * 16;
      uint4 v0, v1;
      asm volatile("global_load_dwordx4 %0, %2, off sc0 sc1\n\t"
                   "global_load_dwordx4 %1, %2, off offset:16 sc0 sc1"
                   : "=&v"(v0), "=&v"(v1) : "v"(g) : "memory");
      asm volatile("s_waitcnt vmcnt(0)" ::: "memory");
      *(uint4*)(Hs + srow * 528 + schunk * 16) = v0;
      *(uint4*)(Hs + srow * 528 + schunk * 16 + 8) = v1;
    }
    __syncthreads();                                     // [B]
    if (t > 0) {
      // recurrent part: 16 MFMA, 2 chains
      #pragma unroll
      for (int ks = 0; ks < 16; ks += 2) {
        short8 a0 = *(const short8*)(Hs + lane16 * 528 + ks * 32 + quad * 8);
        short8 a1 = *(const short8*)(Hs + lane16 * 528 + (ks + 1) * 32 + quad * 8);
        acc0 = __builtin_amdgcn_mfma_f32_16x16x32_bf16(a0, bhh[ks], acc0, 0, 0, 0);
        acc1 = __builtin_amdgcn_mfma_f32_16x16x32_bf16(a1, bhh[ks + 1], acc1, 0, 0, 0);
      }
    }
    #pragma unroll
    for (int rg = 0; rg < 4; ++rg)
      gbuf[w][quad * 4 + rg][lane16] = acc0[rg] + acc1[rg];
    __syncthreads();                                     // [C]
    if (tid < 256) {  // cell update: 2 adjacent hidden units per thread
      const size_t xrow = (size_t)t * 128 + rb + bloc;
      const int hhalf = hp >> 3;
      const int ci = 2 * (hp & 7);
      float g0[4], g1[4];
      #pragma unroll
      for (int g4 = 0; g4 < 4; ++g4) {
        float2 gv = *(const float2*)&gbuf[g4 * 2 + hhalf][bloc][ci];
        g0[g4] = gv.x + bs0[g4];
        g1[g4] = gv.y + bs1[g4];
      }
      float i0 = sigm(g0[0]), f0 = sigm(g0[1]), gg0 = tanhf(g0[2]), o0 = sigm(g0[3]);
      float i1 = sigm(g1[0]), f1 = sigm(g1[1]), gg1 = tanhf(g1[2]), o1 = sigm(g1[3]);
      cs0 = f0 * cs0 + i0 * gg0;
      cs1 = f1 * cs1 + i1 * gg1;
      unsigned hv = pack2bf(o0 * tanhf(cs0), o1 * tanhf(cs1));
      unsigned* ha = (unsigned*)(hout + xrow * 1024 + c * 512 + hs) + hp;
      asm volatile("global_store_dword %0, %1, off sc0 sc1" :: "v"(ha), "v"(hv) : "memory");
    }
    asm volatile("s_waitcnt vmcnt(0)" ::: "memory");
    __syncthreads();                                     // [D]
    if (tid == 0)
      __hip_atomic_fetch_add(&flags[(t * 16 + d) * 16], 1, __ATOMIC_RELAXED,
                             __HIP_MEMORY_SCOPE_AGENT);
  }
}

// ---------------------------------------------------------------- build rep row [target | context | src_e | pad], write target fp32 out
__global__ void build_rep(const int* __restrict__ article, const int* __restrict__ positions,
                          const int* __restrict__ srcs, const float* __restrict__ E,
                          const float* __restrict__ src_emb, const b16* __restrict__ Xg,
                          const b16* __restrict__ h2seq, b16* __restrict__ rep,
                          float* __restrict__ out) {
  int b = blockIdx.x, tid = threadIdx.x;
  int pos = positions[b], sc = srcs[b];
  for (int k = tid; k < 2176; k += 256) {
    b16 v;
    if (k < 1024)      v = Xg[((size_t)pos * 128 + b) * 1024 + k];
    else if (k < 2048) v = h2seq[((size_t)127 * 128 + b) * 1024 + (k - 1024)];
    else if (k < 2148) v = __float2bfloat16(src_emb[sc * 100 + (k - 2048)]);
    else               v = __float2bfloat16(0.0f);
    rep[(size_t)b * 2176 + k] = v;
  }
  int tok = article[b * T_ + pos];
  for (int k = tid; k < 1024; k += 256)
    out[512 + b * 1024 + k] = E[(size_t)tok * 1024 + k];
}

// ---------------------------------------------------------------- logits + probs
__global__ void classifier(const b16* __restrict__ feat, const float* __restrict__ cW,
                           const float* __restrict__ cb, float* __restrict__ out) {
  __shared__ float red[256];
  int tid = threadIdx.x;
  int pairIdx = tid >> 3, jc = tid & 7;
  int bl = pairIdx >> 1, l = pairIdx & 1;
  int b = blockIdx.x * 16 + bl;
  int j0 = jc * 135, j1 = (j0 + 135 < 1074) ? j0 + 135 : 1074;
  float s = 0.f;
  for (int j = j0; j < j1; ++j)
    s += __bfloat162float(feat[(size_t)b * 1152 + j]) * cW[l * 1074 + j];
  red[tid] = s;
  __syncthreads();
  if (jc == 0) {
    float tot = 0.f;
    #pragma unroll
    for (int q = 0; q < 8; ++q) tot += red[pairIdx * 8 + q];
    tot += cb[l];
    out[b * 2 + l] = tot;
    out[256 + b * 2 + l] = 1.0f / (1.0f + __expf(-tot));
  }
}

// ----------------------------------------------------------------
extern "C" void kernel_launch(void* const* d_in, const int* in_sizes, int n_in,
                              void* d_out, int out_size, void* d_ws, size_t ws_size,
                              hipStream_t stream) {
  const int* article = (const int*)d_in[0];
  const int* positions = (const int*)d_in[1];
  const int* srcs = (const int*)d_in[2];
  const float* E = (const float*)d_in[3];
  const float* src_emb = (const float*)d_in[4];
  const float* Wih0f = (const float*)d_in[5];
  const float* Whh0f = (const float*)d_in[6];
  const float* bih0f = (const float*)d_in[7];
  const float* bhh0f = (const float*)d_in[8];
  const float* Wih0b = (const float*)d_in[9];
  const float* Whh0b = (const float*)d_in[10];
  const float* bih0b = (const float*)d_in[11];
  const float* bhh0b = (const float*)d_in[12];
  const float* Wih1f = (const float*)d_in[13];
  const float* Whh1f = (const float*)d_in[14];
  const float* bih1f = (const float*)d_in[15];
  const float* bhh1f = (const float*)d_in[16];
  const float* Wih1b = (const float*)d_in[17];
  const float* Whh1b = (const float*)d_in[18];
  const float* bih1b = (const float*)d_in[19];
  const float* bhh1b = (const float*)d_in[20];
  const float* dW = (const float*)d_in[21];
  const float* db = (const float*)d_in[22];
  const float* cW = (const float*)d_in[23];
  const float* cb = (const float*)d_in[24];

  char* ws = (char*)d_ws;
  size_t off = 0;
  auto carve = [&](size_t bytes) -> void* {
    void* p = ws + off;
    off += (bytes + 255) & ~(size_t)255;
    return p;
  };
  b16* Xg    = (b16*)carve((size_t)16384 * 1024 * 2);
  b16* h1seq = (b16*)carve((size_t)16384 * 1024 * 2);
  b16* h2seq = (b16*)carve((size_t)16384 * 1024 * 2);
  b16* W0cat = (b16*)carve((size_t)4096 * 1024 * 2);
  b16* W1cat = (b16*)carve((size_t)4096 * 1024 * 2);
  b16* Whh0  = (b16*)carve((size_t)2 * 2048 * 512 * 2);
  b16* Whh1  = (b16*)carve((size_t)2 * 2048 * 512 * 2);
  b16* dWpad = (b16*)carve((size_t)1152 * 2176 * 2);
  b16* rep   = (b16*)carve((size_t)128 * 2176 * 2);
  b16* feat  = (b16*)carve((size_t)128 * 1152 * 2);
  float* bias0 = (float*)carve(4096 * 4);
  float* bias1 = (float*)carve(4096 * 4);
  float* dbpad = (float*)carve(1152 * 4);
  int* flags1 = (int*)carve(128 * 16 * 16 * 4);
  int* flags2 = (int*)carve(128 * 16 * 16 * 4);
  (void)ws_size; (void)in_sizes; (void)n_in; (void)out_size;

  hipMemsetAsync(flags1, 0, 2 * 128 * 16 * 16 * 4, stream);

  gather_x<<<16384, 256, 0, stream>>>(article, E, Xg);
  cvt_cat2<<<8192, 256, 0, stream>>>(Wih0f, Wih0b, W0cat, 2048, 1024, 4096 * 1024);
  cvt_cat2<<<8192, 256, 0, stream>>>(Wih1f, Wih1b, W1cat, 2048, 1024, 4096 * 1024);
  cvt_cat2<<<8192, 256, 0, stream>>>(Whh0f, Whh0b, Whh0, 2048, 512, 4096 * 512);
  cvt_cat2<<<8192, 256, 0, stream>>>(Whh1f, Whh1b, Whh1, 2048, 512, 4096 * 512);
  prep_bias<<<16, 256, 0, stream>>>(bih0f, bhh0f, bih0b, bhh0b, bias0);
  prep_bias<<<16, 256, 0, stream>>>(bih1f, bhh1f, bih1b, bhh1b, bias1);
  prep_dw<<<9792, 256, 0, stream>>>(dW, db, dWpad, dbpad);

  // fused input-proj + scan, one launch per layer (GEMMs folded in)
  lstm_scan_f<<<256, 512, 0, stream>>>(Xg, W0cat, Whh0, bias0, h1seq, flags1);
  lstm_scan_f<<<256, 512, 0, stream>>>(h1seq, W1cat, Whh1, bias1, h2seq, flags2);

  build_rep<<<128, 256, 0, stream>>>(article, positions, srcs, E, src_emb, Xg, h2seq, rep,
                                     (float*)d_out);
  gemm_bt<<<dim3(9, 1), 256, 0, stream>>>(rep, dWpad, feat, dbpad, 128, 1152, 2176, 1);
  classifier<<<8, 256, 0, stream>>>(feat, cW, cb, (float*)d_out);
}